// Round 11
// baseline (399.979 us; speedup 1.0000x reference)
//
#include <hip/hip_runtime.h>
#include <hip/hip_bf16.h>

#define S_DIM 4096
#define E_DIM 2048

typedef __attribute__((ext_vector_type(4))) float f32x4;
typedef __attribute__((ext_vector_type(8))) short bf16x8;

__device__ __forceinline__ unsigned short f2bf(float f) {
  unsigned u = __builtin_bit_cast(unsigned, f);
  u += 0x7FFFu + ((u >> 16) & 1u);   // RNE
  return (unsigned short)(u >> 16);
}
__device__ __forceinline__ float bf2f(unsigned short h) {
  return __builtin_bit_cast(float, ((unsigned)h) << 16);
}

// ---------------- cast f32 -> bf16 ----------------
__global__ __launch_bounds__(256) void cast_kernel(const float* __restrict__ in,
                                                   unsigned short* __restrict__ out,
                                                   int n4) {
  int i = blockIdx.x * 256 + threadIdx.x;
  if (i >= n4) return;
  float4 v = reinterpret_cast<const float4*>(in)[i];
  ushort4 o;
  o.x = f2bf(v.x); o.y = f2bf(v.y); o.z = f2bf(v.z); o.w = f2bf(v.w);
  reinterpret_cast<ushort4*>(out)[i] = o;
}

// cast 3 weight matrices into concatenated wcat in one dispatch
__global__ __launch_bounds__(256) void cast3_kernel(const float* __restrict__ w0,
                                                    const float* __restrict__ w1,
                                                    const float* __restrict__ w2,
                                                    unsigned short* __restrict__ out,
                                                    int n4each) {
  int i = blockIdx.x * 256 + threadIdx.x;
  if (i >= 3 * n4each) return;
  const float* src = (i < n4each) ? w0 : (i < 2 * n4each ? w1 : w2);
  int j = (i < n4each) ? i : (i < 2 * n4each ? i - n4each : i - 2 * n4each);
  float4 v = reinterpret_cast<const float4*>(src)[j];
  ushort4 o;
  o.x = f2bf(v.x); o.y = f2bf(v.y); o.z = f2bf(v.z); o.w = f2bf(v.w);
  reinterpret_cast<ushort4*>(out)[i] = o;
}

// ---------------- staging: 128-row x 64-col bf16 half (16 KiB), 256 threads -----
// 16 subtiles of [16 rows][32 bf16] (1024 B), st_16x32 swizzle
// (byte ^= ((byte>>9)&1)<<5). Linear gload_lds dest + inverse-swizzled source.
__device__ __forceinline__ void stage_half128(const unsigned short* __restrict__ g,
                                              int grow0, int ld, int kByte0,
                                              char* base, int tid) {
#pragma unroll
  for (int p = 0; p < 4; ++p) {
    const int o = (p * 256 + tid) * 16;            // linear LDS byte offset 0..16368
    const int S = o >> 10;                         // subtile 0..15
    const int oi = o & 1023;
    const int osi = oi ^ (((oi >> 9) & 1) << 5);   // inverse swizzle on source
    const int r  = (S >> 1) * 16 + (osi >> 6);     // row 0..127
    const int cb = (S & 1) * 64 + (osi & 63);      // byte col 0..127
    const char* ga = reinterpret_cast<const char*>(g) +
                     ((size_t)(grow0 + r) * ld) * 2 + kByte0 + cb;
    char* la = base + (o & ~1023);                 // wave-uniform base; HW adds lane*16
    __builtin_amdgcn_global_load_lds(
        (const __attribute__((address_space(1))) void*)ga,
        (__attribute__((address_space(3))) void*)la, 16, 0, 0);
  }
}

// ================= 128x128 NT GEMM, BK=64, 4 waves, 2 blocks/CU =================
// C = A @ B^T.  LDS 64 KiB: 2 buffers x (A 16K + B 16K).  Per K-tile:
//   PA: 16 ds_read (all frags); bar; lgkm0; 16 MFMA (ks=0); bar
//   PB: stage tile t+2 -> bufc (reads certified done); vmcnt(8) retires t+1;
//       16 MFMA (ks=1, register-only); bar
// Cross-block overlap (2 independent blocks/CU) covers barrier/drain idle.

enum { EPI_QKV = 0, EPI_BF16 = 1, EPI_F32 = 2 };

template <int EPI>
__global__ __launch_bounds__(256, 2) void gemm128(
    const unsigned short* __restrict__ A, const unsigned short* __restrict__ B,
    int lda, int ldb, int K,
    float* __restrict__ Cf, unsigned short* __restrict__ Cb,
    unsigned short* __restrict__ Ct, int ldc, float scale) {
  extern __shared__ char lds[];

  const int tid = threadIdx.x;
  const int rowA0 = blockIdx.y * 128;
  const int rowB0 = blockIdx.x * 128;

  const int wave = tid >> 6;
  const int lane = tid & 63;
  const int wm = wave >> 1;   // 0..1 (M)
  const int wn = wave & 1;    // 0..1 (N)
  const int l15 = lane & 15;
  const int kg = lane >> 4;
  const int rsw = (l15 * 64 + kg * 16) ^ ((l15 & 8) << 2);  // swizzled in-subtile off
  const int aBase = wm * 8192;            // wave's A rowgroup base (4 subtile-pairs)
  const int bBase = 16384 + wn * 8192;    // wave's B rowgroup base

  f32x4 acc[4][4];
#pragma unroll
  for (int mi = 0; mi < 4; ++mi)
#pragma unroll
    for (int ni = 0; ni < 4; ++ni) acc[mi][ni] = (f32x4){0.f, 0.f, 0.f, 0.f};

  const int NT = K / 64;
  char* buf0 = lds;
  char* buf1 = lds + 32768;

  // prologue: stage tile0 -> buf0, tile1 -> buf1 (8 loads/thread each);
  // vmcnt(8) retires tile0; barrier -> tile0 resident for all waves.
  stage_half128(A, rowA0, lda, 0,   buf0 + 0,     tid);
  stage_half128(B, rowB0, ldb, 0,   buf0 + 16384, tid);
  stage_half128(A, rowA0, lda, 128, buf1 + 0,     tid);
  stage_half128(B, rowB0, ldb, 128, buf1 + 16384, tid);
  asm volatile("s_waitcnt vmcnt(8)" ::: "memory");
  __builtin_amdgcn_sched_barrier(0);
  __builtin_amdgcn_s_barrier();

  for (int t = 0; t < NT; ++t) {
    char* bufc = lds + (t & 1) * 32768;
    bf16x8 af[4][2], bf[4][2];

    // ---------- PA: read all 16 frags; bar; lgkm0; MFMA ks=0
#pragma unroll
    for (int mm = 0; mm < 4; ++mm)
#pragma unroll
      for (int ks = 0; ks < 2; ++ks)
        af[mm][ks] = *reinterpret_cast<const bf16x8*>(
            bufc + aBase + (mm * 2 + ks) * 1024 + rsw);
#pragma unroll
    for (int nn = 0; nn < 4; ++nn)
#pragma unroll
      for (int ks = 0; ks < 2; ++ks)
        bf[nn][ks] = *reinterpret_cast<const bf16x8*>(
            bufc + bBase + (nn * 2 + ks) * 1024 + rsw);
    __builtin_amdgcn_sched_barrier(0);
    __builtin_amdgcn_s_barrier();   // all waves' reads issued
    asm volatile("s_waitcnt lgkmcnt(0)" ::: "memory");
    __builtin_amdgcn_sched_barrier(0);
    __builtin_amdgcn_s_setprio(1);
#pragma unroll
    for (int mm = 0; mm < 4; ++mm)
#pragma unroll
      for (int nn = 0; nn < 4; ++nn)
        acc[mm][nn] = __builtin_amdgcn_mfma_f32_16x16x32_bf16(
            af[mm][0], bf[nn][0], acc[mm][nn], 0, 0, 0);
    __builtin_amdgcn_s_setprio(0);
    __builtin_amdgcn_s_barrier();   // certifies ALL waves' bufc reads retired

    // ---------- PB: stage t+2 -> bufc; vmcnt(8) retires t+1; MFMA ks=1 (reg-only)
    if (t + 2 < NT) {
      const int kb = (t + 2) * 128;
      stage_half128(A, rowA0, lda, kb, bufc + 0,     tid);
      stage_half128(B, rowB0, ldb, kb, bufc + 16384, tid);
      asm volatile("s_waitcnt vmcnt(8)" ::: "memory");
    } else {
      asm volatile("s_waitcnt vmcnt(0)" ::: "memory");
    }
    __builtin_amdgcn_sched_barrier(0);
    __builtin_amdgcn_s_setprio(1);
#pragma unroll
    for (int mm = 0; mm < 4; ++mm)
#pragma unroll
      for (int nn = 0; nn < 4; ++nn)
        acc[mm][nn] = __builtin_amdgcn_mfma_f32_16x16x32_bf16(
            af[mm][1], bf[nn][1], acc[mm][nn], 0, 0, 0);
    __builtin_amdgcn_s_setprio(0);
    __builtin_amdgcn_sched_barrier(0);
    __builtin_amdgcn_s_barrier();   // all waves passed vmcnt -> tile t+1 resident
  }

  // ---------- epilogue: C/D frag mapping col=lane&15, row=(lane>>4)*4+reg
  const int r0 = rowA0 + wm * 64;
  const int c0 = rowB0 + wn * 64;
#pragma unroll
  for (int mi = 0; mi < 4; ++mi) {
    const int row = r0 + mi * 16 + kg * 4;
#pragma unroll
    for (int ni = 0; ni < 4; ++ni) {
      const int col = c0 + ni * 16 + l15;
      f32x4 v = acc[mi][ni];
      if constexpr (EPI == EPI_F32) {
#pragma unroll
        for (int r = 0; r < 4; ++r)
          Cf[(size_t)(row + r) * ldc + col] = v[r];
      } else if constexpr (EPI == EPI_BF16) {
#pragma unroll
        for (int r = 0; r < 4; ++r)
          Cb[(size_t)(row + r) * ldc + col] = f2bf(v[r] * scale);
      } else {  // EPI_QKV: cols<4096 -> qkb [4096][4096]; cols>=4096 -> vt transposed
        if (rowB0 < 4096) {
#pragma unroll
          for (int r = 0; r < 4; ++r)
            Cb[(size_t)(row + r) * 4096 + col] = f2bf(v[r]);
        } else {
          ushort4 pk;
          pk.x = f2bf(v[0]); pk.y = f2bf(v[1]);
          pk.z = f2bf(v[2]); pk.w = f2bf(v[3]);
          *reinterpret_cast<ushort4*>(Ct + (size_t)(col - 4096) * 4096 + row) = pk;
        }
      }
    }
  }
}

// ---------------- row softmax: S (bf16 [4096][4096]) -> P (bf16) ----------------
__global__ __launch_bounds__(256) void softmax_kernel(const unsigned short* __restrict__ Sm,
                                                      unsigned short* __restrict__ P) {
  const int row = blockIdx.x;
  const int tid = threadIdx.x;
  const unsigned short* src = Sm + (size_t)row * S_DIM;
  float vals[16];
  float mx = -1e30f;
#pragma unroll
  for (int i = 0; i < 4; ++i) {
    ushort4 h = reinterpret_cast<const ushort4*>(src)[tid + i * 256];
    float a = bf2f(h.x), b = bf2f(h.y), c = bf2f(h.z), d = bf2f(h.w);
    vals[i * 4 + 0] = a; vals[i * 4 + 1] = b;
    vals[i * 4 + 2] = c; vals[i * 4 + 3] = d;
    mx = fmaxf(mx, fmaxf(fmaxf(a, b), fmaxf(c, d)));
  }
#pragma unroll
  for (int off = 32; off >= 1; off >>= 1) mx = fmaxf(mx, __shfl_xor(mx, off, 64));
  __shared__ float red[8];
  const int wave = tid >> 6, lane = tid & 63;
  if (lane == 0) red[wave] = mx;
  __syncthreads();
  mx = fmaxf(fmaxf(red[0], red[1]), fmaxf(red[2], red[3]));
  float sum = 0.f;
#pragma unroll
  for (int i = 0; i < 16; ++i) { vals[i] = __expf(vals[i] - mx); sum += vals[i]; }
#pragma unroll
  for (int off = 32; off >= 1; off >>= 1) sum += __shfl_xor(sum, off, 64);
  if (lane == 0) red[4 + wave] = sum;
  __syncthreads();
  sum = red[4] + red[5] + red[6] + red[7];
  const float inv = 1.0f / sum;
  unsigned short* dst = P + (size_t)row * S_DIM;
#pragma unroll
  for (int i = 0; i < 4; ++i) {
    ushort4 pk;
    pk.x = f2bf(vals[i * 4 + 0] * inv);
    pk.y = f2bf(vals[i * 4 + 1] * inv);
    pk.z = f2bf(vals[i * 4 + 2] * inv);
    pk.w = f2bf(vals[i * 4 + 3] * inv);
    reinterpret_cast<ushort4*>(dst)[tid + i * 256] = pk;
  }
}

extern "C" void kernel_launch(void* const* d_in, const int* in_sizes, int n_in,
                              void* d_out, int out_size, void* d_ws, size_t ws_size,
                              hipStream_t stream) {
  const float* x  = (const float*)d_in[0];
  const float* Wq = (const float*)d_in[1];
  const float* Wk = (const float*)d_in[2];
  const float* Wv = (const float*)d_in[3];
  float* out = (float*)d_out;
  char* ws = (char*)d_ws;

  const size_t MB = 1024 * 1024;
  const size_t NEED = 120 * MB;
  if (ws_size < NEED) return;  // visible absmax failure instead of OOB crash

  // Layout (120 MiB):
  //   [0,16)   xb bf16 [4096][2048]
  //   [16,40)  wcat bf16 [6144][2048]
  //   [40,72)  qkb bf16 [4096][4096] (Q cols 0-2047, K cols 2048-4095) -> P after QK
  //   [72,88)  vt bf16 [2048][4096]
  //   [88,120) Sb bf16 [4096][4096]
  unsigned short* xb   = (unsigned short*)(ws);
  unsigned short* wcat = (unsigned short*)(ws + 16 * MB);
  unsigned short* qkb  = (unsigned short*)(ws + 40 * MB);
  unsigned short* vt   = (unsigned short*)(ws + 72 * MB);
  unsigned short* Sb   = (unsigned short*)(ws + 88 * MB);
  unsigned short* P = qkb;

  // dynamic LDS attribute (host-side, graph-capture-safe)
  hipFuncSetAttribute(reinterpret_cast<const void*>(&gemm128<EPI_QKV>),
                      hipFuncAttributeMaxDynamicSharedMemorySize, 65536);
  hipFuncSetAttribute(reinterpret_cast<const void*>(&gemm128<EPI_BF16>),
                      hipFuncAttributeMaxDynamicSharedMemorySize, 65536);
  hipFuncSetAttribute(reinterpret_cast<const void*>(&gemm128<EPI_F32>),
                      hipFuncAttributeMaxDynamicSharedMemorySize, 65536);

  const int nx4 = S_DIM * E_DIM / 4;
  const int nw4 = E_DIM * E_DIM / 4;

  // 1) casts
  cast_kernel<<<nx4 / 256, 256, 0, stream>>>(x, xb, nx4);
  cast3_kernel<<<3 * nw4 / 256, 256, 0, stream>>>(Wq, Wk, Wv, wcat, nw4);

  // 2) fused QKV projection: [4096][6144] = xb @ wcat^T; V-range written transposed
  //    grid 48x32 = 1536 blocks = 3 exact rounds at 2 blocks/CU
  gemm128<EPI_QKV><<<dim3(48, 32), 256, 65536, stream>>>(
      xb, wcat, E_DIM, E_DIM, E_DIM, nullptr, qkb, vt, 4096, 1.0f);

  // 3) S = (Q @ K^T) * 1/sqrt(E) -> bf16   (grid 1024 = 2 exact rounds)
  const float scale = 0.022097086912079608f;
  gemm128<EPI_BF16><<<dim3(32, 32), 256, 65536, stream>>>(
      qkb, qkb + 2048, 4096, 4096, E_DIM, nullptr, Sb, nullptr, 4096, scale);

  // 4) softmax -> P (aliases dead qkb)
  softmax_kernel<<<S_DIM, 256, 0, stream>>>(Sb, P);

  // 5) out = P @ vt^T  (f32 direct; grid 512 = 1 exact round)
  gemm128<EPI_F32><<<dim3(16, 32), 256, 65536, stream>>>(
      P, vt, 4096, 4096, S_DIM, out, nullptr, nullptr, E_DIM, 1.0f);
}

// Round 12
// 373.670 us; speedup vs baseline: 1.0704x; 1.0704x over previous
//
#include <hip/hip_runtime.h>
#include <hip/hip_bf16.h>

#define S_DIM 4096
#define E_DIM 2048

typedef __attribute__((ext_vector_type(4))) float f32x4;
typedef __attribute__((ext_vector_type(8))) short bf16x8;

__device__ __forceinline__ unsigned short f2bf(float f) {
  unsigned u = __builtin_bit_cast(unsigned, f);
  u += 0x7FFFu + ((u >> 16) & 1u);   // RNE
  return (unsigned short)(u >> 16);
}
__device__ __forceinline__ float bf2f(unsigned short h) {
  return __builtin_bit_cast(float, ((unsigned)h) << 16);
}

// ---------------- cast f32 -> bf16 ----------------
__global__ __launch_bounds__(256) void cast_kernel(const float* __restrict__ in,
                                                   unsigned short* __restrict__ out,
                                                   int n4) {
  int i = blockIdx.x * 256 + threadIdx.x;
  if (i >= n4) return;
  float4 v = reinterpret_cast<const float4*>(in)[i];
  ushort4 o;
  o.x = f2bf(v.x); o.y = f2bf(v.y); o.z = f2bf(v.z); o.w = f2bf(v.w);
  reinterpret_cast<ushort4*>(out)[i] = o;
}

// cast 3 weight matrices into concatenated wcat in one dispatch
__global__ __launch_bounds__(256) void cast3_kernel(const float* __restrict__ w0,
                                                    const float* __restrict__ w1,
                                                    const float* __restrict__ w2,
                                                    unsigned short* __restrict__ out,
                                                    int n4each) {
  int i = blockIdx.x * 256 + threadIdx.x;
  if (i >= 3 * n4each) return;
  const float* src = (i < n4each) ? w0 : (i < 2 * n4each ? w1 : w2);
  int j = (i < n4each) ? i : (i < 2 * n4each ? i - n4each : i - 2 * n4each);
  float4 v = reinterpret_cast<const float4*>(src)[j];
  ushort4 o;
  o.x = f2bf(v.x); o.y = f2bf(v.y); o.z = f2bf(v.z); o.w = f2bf(v.w);
  reinterpret_cast<ushort4*>(out)[i] = o;
}

// ---------------- staging (512-thread blocks): 128x64 bf16 half (16 KiB) --------
// 16 subtiles of [16 rows][32 bf16] (1024 B), st_16x32 swizzle
// (byte ^= ((byte>>9)&1)<<5). Linear gload_lds dest + inverse-swizzled source.
__device__ __forceinline__ void stage_half(const unsigned short* __restrict__ g,
                                           int grow0, int ld, int kByte0,
                                           char* ldsHalfBase, int tid) {
#pragma unroll
  for (int p = 0; p < 2; ++p) {
    const int o = (p * 512 + tid) * 16;
    const int S = o >> 10;
    const int oi = o & 1023;
    const int osi = oi ^ (((oi >> 9) & 1) << 5);
    const int r  = (S >> 1) * 16 + (osi >> 6);
    const int cb = (S & 1) * 64 + (osi & 63);
    const char* ga = reinterpret_cast<const char*>(g) +
                     ((size_t)(grow0 + r) * ld) * 2 + kByte0 + cb;
    char* la = ldsHalfBase + (o & ~1023);
    __builtin_amdgcn_global_load_lds(
        (const __attribute__((address_space(1))) void*)ga,
        (__attribute__((address_space(3))) void*)la, 16, 0, 0);
  }
}

// ---------------- staging (256-thread blocks): same layout --------
__device__ __forceinline__ void stage_half128(const unsigned short* __restrict__ g,
                                              int grow0, int ld, int kByte0,
                                              char* base, int tid) {
#pragma unroll
  for (int p = 0; p < 4; ++p) {
    const int o = (p * 256 + tid) * 16;
    const int S = o >> 10;
    const int oi = o & 1023;
    const int osi = oi ^ (((oi >> 9) & 1) << 5);
    const int r  = (S >> 1) * 16 + (osi >> 6);
    const int cb = (S & 1) * 64 + (osi & 63);
    const char* ga = reinterpret_cast<const char*>(g) +
                     ((size_t)(grow0 + r) * ld) * 2 + kByte0 + cb;
    char* la = base + (o & ~1023);
    __builtin_amdgcn_global_load_lds(
        (const __attribute__((address_space(1))) void*)ga,
        (__attribute__((address_space(3))) void*)la, 16, 0, 0);
  }
}

// =============== QK: 2-phase 256x256 NT GEMM, 8 waves, 1 block/CU ===============
// (rounds 6-9 best-measured config: 74 us, 929 TF at grid 16x16)
#define MFMA_HALF(AM, AF)                                                      \
  _Pragma("unroll") for (int ks = 0; ks < 2; ++ks)                             \
  _Pragma("unroll") for (int mm = 0; mm < 4; ++mm) {                           \
    acc[(AM) + mm][0] = __builtin_amdgcn_mfma_f32_16x16x32_bf16(               \
        AF[mm][ks], b0[0][ks], acc[(AM) + mm][0], 0, 0, 0);                    \
    acc[(AM) + mm][1] = __builtin_amdgcn_mfma_f32_16x16x32_bf16(               \
        AF[mm][ks], b0[1][ks], acc[(AM) + mm][1], 0, 0, 0);                    \
    acc[(AM) + mm][2] = __builtin_amdgcn_mfma_f32_16x16x32_bf16(               \
        AF[mm][ks], b1[0][ks], acc[(AM) + mm][2], 0, 0, 0);                    \
    acc[(AM) + mm][3] = __builtin_amdgcn_mfma_f32_16x16x32_bf16(               \
        AF[mm][ks], b1[1][ks], acc[(AM) + mm][3], 0, 0, 0);                    \
  }

#define READ_A0Q(dst, buf)                                                     \
  _Pragma("unroll") for (int mm = 0; mm < 4; ++mm)                             \
  _Pragma("unroll") for (int ks = 0; ks < 2; ++ks)                             \
    dst[mm][ks] = *reinterpret_cast<const bf16x8*>(                            \
        (buf) + aBase + (mm * 2 + ks) * 1024 + rsw);

#define READ_A1Q(dst, buf)                                                     \
  _Pragma("unroll") for (int mm = 0; mm < 4; ++mm)                             \
  _Pragma("unroll") for (int ks = 0; ks < 2; ++ks)                             \
    dst[mm][ks] = *reinterpret_cast<const bf16x8*>(                            \
        (buf) + aBase + ((4 + mm) * 2 + ks) * 1024 + rsw);

#define READ_BQ(dst, buf, nh)                                                  \
  _Pragma("unroll") for (int nn = 0; nn < 2; ++nn)                             \
  _Pragma("unroll") for (int ks = 0; ks < 2; ++ks)                             \
    dst[nn][ks] = *reinterpret_cast<const bf16x8*>(                            \
        (buf) + bSub[nh][nn] + ks * 1024 + rsw);

__global__ __launch_bounds__(512, 2) void gemm8(
    const unsigned short* __restrict__ A, const unsigned short* __restrict__ B,
    int lda, int ldb, int K,
    unsigned short* __restrict__ Cb, int ldc, float scale) {
  extern __shared__ char lds[];

  const int tid = threadIdx.x;
  const int rowA0 = blockIdx.y * 256;   // by = M, bx = N (round-6/9 orientation)
  const int rowB0 = blockIdx.x * 256;

  const int wave = tid >> 6;
  const int lane = tid & 63;
  const int wm = wave >> 2;
  const int wn = wave & 3;
  const int l15 = lane & 15;
  const int kg = lane >> 4;
  const int rsw = (l15 * 64 + kg * 16) ^ ((l15 & 8) << 2);

  int bSub[2][2];
#pragma unroll
  for (int nh = 0; nh < 2; ++nh)
#pragma unroll
    for (int nn = 0; nn < 2; ++nn) {
      const int row = wn * 64 + nh * 32 + nn * 16;
      bSub[nh][nn] = 32768 + (row >> 7) * 16384 + ((row & 127) >> 4) * 2048;
    }
  const int aBase = wm * 16384;

  f32x4 acc[8][4];
#pragma unroll
  for (int mi = 0; mi < 8; ++mi)
#pragma unroll
    for (int ni = 0; ni < 4; ++ni) acc[mi][ni] = (f32x4){0.f, 0.f, 0.f, 0.f};

  const int NT = K / 64;
  char* buf0 = lds;
  char* buf1 = lds + 65536;

  stage_half(B, rowB0,       ldb, 0,   buf0 + 32768, tid);
  stage_half(B, rowB0 + 128, ldb, 0,   buf0 + 49152, tid);
  stage_half(A, rowA0,       lda, 0,   buf0 + 0,     tid);
  stage_half(A, rowA0 + 128, lda, 0,   buf0 + 16384, tid);
  stage_half(B, rowB0,       ldb, 128, buf1 + 32768, tid);
  stage_half(B, rowB0 + 128, ldb, 128, buf1 + 49152, tid);
  stage_half(A, rowA0,       lda, 128, buf1 + 0,     tid);
  asm volatile("s_waitcnt vmcnt(6)" ::: "memory");
  __builtin_amdgcn_sched_barrier(0);
  __builtin_amdgcn_s_barrier();

  for (int t = 0; t < NT; ++t) {
    char* bufc = lds + (t & 1) * 65536;
    char* bufn = lds + ((t & 1) ^ 1) * 65536;
    bf16x8 a0[4][2], a1[4][2], b0[2][2], b1[2][2];

    // PA
    READ_A0Q(a0, bufc)
    READ_BQ(b0, bufc, 0)
    READ_BQ(b1, bufc, 1)
    if (t + 1 < NT)
      stage_half(A, rowA0 + 128, lda, (t + 1) * 128, bufn + 16384, tid);
    __builtin_amdgcn_sched_barrier(0);
    __builtin_amdgcn_s_barrier();
    asm volatile("s_waitcnt lgkmcnt(0)" ::: "memory");
    __builtin_amdgcn_sched_barrier(0);
    __builtin_amdgcn_s_setprio(1);
    MFMA_HALF(0, a0)
    __builtin_amdgcn_s_setprio(0);
    __builtin_amdgcn_s_barrier();

    // PB
    READ_A1Q(a1, bufc)
    if (t + 2 < NT) {
      const int kb = (t + 2) * 128;
      stage_half(B, rowB0,       ldb, kb, bufc + 32768, tid);
      stage_half(B, rowB0 + 128, ldb, kb, bufc + 49152, tid);
      stage_half(A, rowA0,       lda, kb, bufc + 0,     tid);
      asm volatile("s_waitcnt vmcnt(6)" ::: "memory");
    } else {
      asm volatile("s_waitcnt vmcnt(0)" ::: "memory");
    }
    __builtin_amdgcn_sched_barrier(0);
    __builtin_amdgcn_s_barrier();
    asm volatile("s_waitcnt lgkmcnt(0)" ::: "memory");
    __builtin_amdgcn_sched_barrier(0);
    __builtin_amdgcn_s_setprio(1);
    MFMA_HALF(4, a1)
    __builtin_amdgcn_s_setprio(0);
    __builtin_amdgcn_s_barrier();
  }

  const int r0 = rowA0 + wm * 128;
  const int c0 = rowB0 + wn * 64;
#pragma unroll
  for (int mi = 0; mi < 8; ++mi) {
    const int row = r0 + (mi >> 2) * 64 + (mi & 3) * 16 + kg * 4;
#pragma unroll
    for (int ni = 0; ni < 4; ++ni) {
      const int col = c0 + (ni >> 1) * 32 + (ni & 1) * 16 + l15;
      f32x4 v = acc[mi][ni];
#pragma unroll
      for (int r = 0; r < 4; ++r)
        Cb[(size_t)(row + r) * ldc + col] = f2bf(v[r] * scale);
    }
  }
}

// ============ proj/PV: 128x128 NT GEMM, BK=64, 4 waves, 2 blocks/CU ============
enum { EPI_QKV = 0, EPI_BF16 = 1, EPI_F32 = 2 };

template <int EPI>
__global__ __launch_bounds__(256, 2) void gemm128(
    const unsigned short* __restrict__ A, const unsigned short* __restrict__ B,
    int lda, int ldb, int K,
    float* __restrict__ Cf, unsigned short* __restrict__ Cb,
    unsigned short* __restrict__ Ct, int ldc, float scale) {
  extern __shared__ char lds[];

  const int tid = threadIdx.x;
  const int rowA0 = blockIdx.y * 128;
  const int rowB0 = blockIdx.x * 128;

  const int wave = tid >> 6;
  const int lane = tid & 63;
  const int wm = wave >> 1;
  const int wn = wave & 1;
  const int l15 = lane & 15;
  const int kg = lane >> 4;
  const int rsw = (l15 * 64 + kg * 16) ^ ((l15 & 8) << 2);
  const int aBase = wm * 8192;
  const int bBase = 16384 + wn * 8192;

  f32x4 acc[4][4];
#pragma unroll
  for (int mi = 0; mi < 4; ++mi)
#pragma unroll
    for (int ni = 0; ni < 4; ++ni) acc[mi][ni] = (f32x4){0.f, 0.f, 0.f, 0.f};

  const int NT = K / 64;
  char* buf0 = lds;
  char* buf1 = lds + 32768;

  stage_half128(A, rowA0, lda, 0,   buf0 + 0,     tid);
  stage_half128(B, rowB0, ldb, 0,   buf0 + 16384, tid);
  stage_half128(A, rowA0, lda, 128, buf1 + 0,     tid);
  stage_half128(B, rowB0, ldb, 128, buf1 + 16384, tid);
  asm volatile("s_waitcnt vmcnt(8)" ::: "memory");
  __builtin_amdgcn_sched_barrier(0);
  __builtin_amdgcn_s_barrier();

  for (int t = 0; t < NT; ++t) {
    char* bufc = lds + (t & 1) * 32768;
    bf16x8 af[4][2], bf[4][2];

    // PA: read all frags; bar; lgkm0; MFMA ks=0
#pragma unroll
    for (int mm = 0; mm < 4; ++mm)
#pragma unroll
      for (int ks = 0; ks < 2; ++ks)
        af[mm][ks] = *reinterpret_cast<const bf16x8*>(
            bufc + aBase + (mm * 2 + ks) * 1024 + rsw);
#pragma unroll
    for (int nn = 0; nn < 4; ++nn)
#pragma unroll
      for (int ks = 0; ks < 2; ++ks)
        bf[nn][ks] = *reinterpret_cast<const bf16x8*>(
            bufc + bBase + (nn * 2 + ks) * 1024 + rsw);
    __builtin_amdgcn_sched_barrier(0);
    __builtin_amdgcn_s_barrier();
    asm volatile("s_waitcnt lgkmcnt(0)" ::: "memory");
    __builtin_amdgcn_sched_barrier(0);
    __builtin_amdgcn_s_setprio(1);
#pragma unroll
    for (int mm = 0; mm < 4; ++mm)
#pragma unroll
      for (int nn = 0; nn < 4; ++nn)
        acc[mm][nn] = __builtin_amdgcn_mfma_f32_16x16x32_bf16(
            af[mm][0], bf[nn][0], acc[mm][nn], 0, 0, 0);
    __builtin_amdgcn_s_setprio(0);
    __builtin_amdgcn_s_barrier();

    // PB: stage t+2; vmcnt(8); MFMA ks=1
    if (t + 2 < NT) {
      const int kb = (t + 2) * 128;
      stage_half128(A, rowA0, lda, kb, bufc + 0,     tid);
      stage_half128(B, rowB0, ldb, kb, bufc + 16384, tid);
      asm volatile("s_waitcnt vmcnt(8)" ::: "memory");
    } else {
      asm volatile("s_waitcnt vmcnt(0)" ::: "memory");
    }
    __builtin_amdgcn_sched_barrier(0);
    __builtin_amdgcn_s_setprio(1);
#pragma unroll
    for (int mm = 0; mm < 4; ++mm)
#pragma unroll
      for (int nn = 0; nn < 4; ++nn)
        acc[mm][nn] = __builtin_amdgcn_mfma_f32_16x16x32_bf16(
            af[mm][1], bf[nn][1], acc[mm][nn], 0, 0, 0);
    __builtin_amdgcn_s_setprio(0);
    __builtin_amdgcn_sched_barrier(0);
    __builtin_amdgcn_s_barrier();
  }

  const int r0 = rowA0 + wm * 64;
  const int c0 = rowB0 + wn * 64;
#pragma unroll
  for (int mi = 0; mi < 4; ++mi) {
    const int row = r0 + mi * 16 + kg * 4;
#pragma unroll
    for (int ni = 0; ni < 4; ++ni) {
      const int col = c0 + ni * 16 + l15;
      f32x4 v = acc[mi][ni];
      if constexpr (EPI == EPI_F32) {
#pragma unroll
        for (int r = 0; r < 4; ++r)
          Cf[(size_t)(row + r) * ldc + col] = v[r];
      } else if constexpr (EPI == EPI_BF16) {
#pragma unroll
        for (int r = 0; r < 4; ++r)
          Cb[(size_t)(row + r) * ldc + col] = f2bf(v[r] * scale);
      } else {  // EPI_QKV
        if (rowB0 < 4096) {
#pragma unroll
          for (int r = 0; r < 4; ++r)
            Cb[(size_t)(row + r) * 4096 + col] = f2bf(v[r]);
        } else {
          ushort4 pk;
          pk.x = f2bf(v[0]); pk.y = f2bf(v[1]);
          pk.z = f2bf(v[2]); pk.w = f2bf(v[3]);
          *reinterpret_cast<ushort4*>(Ct + (size_t)(col - 4096) * 4096 + row) = pk;
        }
      }
    }
  }
}

// ---------------- row softmax: S (bf16 [4096][4096]) -> P (bf16) ----------------
__global__ __launch_bounds__(256) void softmax_kernel(const unsigned short* __restrict__ Sm,
                                                      unsigned short* __restrict__ P) {
  const int row = blockIdx.x;
  const int tid = threadIdx.x;
  const unsigned short* src = Sm + (size_t)row * S_DIM;
  float vals[16];
  float mx = -1e30f;
#pragma unroll
  for (int i = 0; i < 4; ++i) {
    ushort4 h = reinterpret_cast<const ushort4*>(src)[tid + i * 256];
    float a = bf2f(h.x), b = bf2f(h.y), c = bf2f(h.z), d = bf2f(h.w);
    vals[i * 4 + 0] = a; vals[i * 4 + 1] = b;
    vals[i * 4 + 2] = c; vals[i * 4 + 3] = d;
    mx = fmaxf(mx, fmaxf(fmaxf(a, b), fmaxf(c, d)));
  }
#pragma unroll
  for (int off = 32; off >= 1; off >>= 1) mx = fmaxf(mx, __shfl_xor(mx, off, 64));
  __shared__ float red[8];
  const int wave = tid >> 6, lane = tid & 63;
  if (lane == 0) red[wave] = mx;
  __syncthreads();
  mx = fmaxf(fmaxf(red[0], red[1]), fmaxf(red[2], red[3]));
  float sum = 0.f;
#pragma unroll
  for (int i = 0; i < 16; ++i) { vals[i] = __expf(vals[i] - mx); sum += vals[i]; }
#pragma unroll
  for (int off = 32; off >= 1; off >>= 1) sum += __shfl_xor(sum, off, 64);
  if (lane == 0) red[4 + wave] = sum;
  __syncthreads();
  sum = red[4] + red[5] + red[6] + red[7];
  const float inv = 1.0f / sum;
  unsigned short* dst = P + (size_t)row * S_DIM;
#pragma unroll
  for (int i = 0; i < 4; ++i) {
    ushort4 pk;
    pk.x = f2bf(vals[i * 4 + 0] * inv);
    pk.y = f2bf(vals[i * 4 + 1] * inv);
    pk.z = f2bf(vals[i * 4 + 2] * inv);
    pk.w = f2bf(vals[i * 4 + 3] * inv);
    reinterpret_cast<ushort4*>(dst)[tid + i * 256] = pk;
  }
}

extern "C" void kernel_launch(void* const* d_in, const int* in_sizes, int n_in,
                              void* d_out, int out_size, void* d_ws, size_t ws_size,
                              hipStream_t stream) {
  const float* x  = (const float*)d_in[0];
  const float* Wq = (const float*)d_in[1];
  const float* Wk = (const float*)d_in[2];
  const float* Wv = (const float*)d_in[3];
  float* out = (float*)d_out;
  char* ws = (char*)d_ws;

  const size_t MB = 1024 * 1024;
  const size_t NEED = 120 * MB;
  if (ws_size < NEED) return;  // visible absmax failure instead of OOB crash

  // Layout (120 MiB):
  //   [0,16)   xb bf16 [4096][2048]
  //   [16,40)  wcat bf16 [6144][2048]
  //   [40,72)  qkb bf16 [4096][4096] (Q cols 0-2047, K cols 2048-4095) -> P after QK
  //   [72,88)  vt bf16 [2048][4096]
  //   [88,120) Sb bf16 [4096][4096]
  unsigned short* xb   = (unsigned short*)(ws);
  unsigned short* wcat = (unsigned short*)(ws + 16 * MB);
  unsigned short* qkb  = (unsigned short*)(ws + 40 * MB);
  unsigned short* vt   = (unsigned short*)(ws + 72 * MB);
  unsigned short* Sb   = (unsigned short*)(ws + 88 * MB);
  unsigned short* P = qkb;

  hipFuncSetAttribute(reinterpret_cast<const void*>(&gemm8),
                      hipFuncAttributeMaxDynamicSharedMemorySize, 131072);
  hipFuncSetAttribute(reinterpret_cast<const void*>(&gemm128<EPI_QKV>),
                      hipFuncAttributeMaxDynamicSharedMemorySize, 65536);
  hipFuncSetAttribute(reinterpret_cast<const void*>(&gemm128<EPI_F32>),
                      hipFuncAttributeMaxDynamicSharedMemorySize, 65536);

  const int nx4 = S_DIM * E_DIM / 4;
  const int nw4 = E_DIM * E_DIM / 4;

  // 1) casts
  cast_kernel<<<nx4 / 256, 256, 0, stream>>>(x, xb, nx4);
  cast3_kernel<<<3 * nw4 / 256, 256, 0, stream>>>(Wq, Wk, Wv, wcat, nw4);

  // 2) fused QKV projection (best-measured: 128^2, 2 blocks/CU, grid 48x32)
  gemm128<EPI_QKV><<<dim3(48, 32), 256, 65536, stream>>>(
      xb, wcat, E_DIM, E_DIM, E_DIM, nullptr, qkb, vt, 4096, 1.0f);

  // 3) S = (Q @ K^T) * 1/sqrt(E) (best-measured: 256^2 2-phase, grid 16x16, bx=N)
  const float scale = 0.022097086912079608f;
  gemm8<<<dim3(16, 16), 512, 131072, stream>>>(
      qkb, qkb + 2048, 4096, 4096, E_DIM, Sb, 4096, scale);

  // 4) softmax -> P (aliases dead qkb)
  softmax_kernel<<<S_DIM, 256, 0, stream>>>(Sb, P);

  // 5) out = P @ vt^T  (128^2, 2 blocks/CU, grid 16x32 = exact 1 round)
  gemm128<EPI_F32><<<dim3(16, 32), 256, 65536, stream>>>(
      P, vt, 4096, 4096, S_DIM, out, nullptr, nullptr, E_DIM, 1.0f);
}